// Round 14
// baseline (195.941 us; speedup 1.0000x reference)
//
#include <hip/hip_runtime.h>

// B=2, S=4096, D=512, H=8, HD=64. fp32 in/out; bf16 MFMA internally.
// ws (27 MiB): qy[2][4096][8][64] (Q, then Y in-place) | Kf frag-major |
//              Vf frag-major | (unused) | wqkvb bf16 | wob bf16
// d_out (16 MiB): xb bf16 scratch (dead after gemm1), then fp32 out.
// attn uses ZERO-MAX softmax in exp2 domain: p = exp2(s); o and l scale
// together (ratio invariant).
// r14: REVERT to r10's verified 2-wave merge topology (r11-r13's 4-wave merge
// NaN'd 3x -- structure abandoned per template discipline). TLP doubled
// instead via 16-row q-tiles: 256 tiles, pairs {p,255-p}, nt(p)=(p>>2)+1 ->
// every pair exactly 65 k-tiles. Grid (16,128) x 128 thr = 4096 waves =
// 4/SIMD (vs r10's 2). Single Q-frag per wave; same asm GLD + counted-vmcnt
// ladder (WAITV constants re-verified for the 2-GLD Q prologue). Block =
// 2 waves (wave = k-half of the pair's range); wave1 -> LDS (o,l); wave0
// sums, normalizes, writes Y in-place. gemm1/gemm_o/cvt byte-frozen from r10.

typedef __bf16 bf16x8 __attribute__((ext_vector_type(8)));
typedef float f32x4 __attribute__((ext_vector_type(4)));
typedef unsigned short u16;

#define MFMA(a, b, c) __builtin_amdgcn_mfma_f32_16x16x32_bf16(a, b, c, 0, 0, 0)
#define QSCALE 0.18033688011112042f   // 1/sqrt(64) * log2(e)

__device__ __forceinline__ float exp2_fast(float x) {
    return __builtin_amdgcn_exp2f(x);
}
__device__ __forceinline__ u16 f2bf(float f) {
    union { __bf16 h; u16 u; } v; v.h = (__bf16)f; return v.u;
}
__device__ __forceinline__ ushort4 f4_to_bf4(float4 v) {
    ushort4 r;
    r.x = f2bf(v.x); r.y = f2bf(v.y); r.z = f2bf(v.z); r.w = f2bf(v.w);
    return r;
}
__device__ __forceinline__ void load_lds16(const u16* g, u16* l) {
    __builtin_amdgcn_global_load_lds(
        (const __attribute__((address_space(1))) void*)g,
        (__attribute__((address_space(3))) void*)l, 16, 0, 0);
}

// ---------------------------------------------------------------------------
// One fused fp32->bf16 convert for x, Wqkv, Wo
// ---------------------------------------------------------------------------
__global__ __launch_bounds__(256) void cvt_all(
    const float* __restrict__ x, const float* __restrict__ wq,
    const float* __restrict__ wo,
    u16* __restrict__ xb, u16* __restrict__ wqb, u16* __restrict__ wob)
{
    int i = blockIdx.x * 256 + threadIdx.x;
    if (i < 1048576) {
        ((ushort4*)xb)[i] = f4_to_bf4(((const float4*)x)[i]);
    } else if (i < 1048576 + 196608) {
        int j = i - 1048576;
        ((ushort4*)wqb)[j] = f4_to_bf4(((const float4*)wq)[j]);
    } else {
        int j = i - 1048576 - 196608;
        ((ushort4*)wob)[j] = f4_to_bf4(((const float4*)wo)[j]);
    }
}

// ---------------------------------------------------------------------------
// GEMM1: qkv = x @ Wqkv^T + b. Q/K blocks: operand-swapped (C^T) epilogue.
// V blocks (bn>=1024): NON-swapped MFMA -> C rows = s (r-contiguous), cols = d
// -> Vf fragment write is 16 aligned ushort4 stores.
// ---------------------------------------------------------------------------
__global__ __launch_bounds__(256) void gemm_qkv_bf(
    const u16* __restrict__ X, const u16* __restrict__ W,
    const float* __restrict__ bias,
    u16* __restrict__ QY, u16* __restrict__ Kf, u16* __restrict__ Vf)
{
    __shared__ u16 As[2 * 128 * 32];
    __shared__ u16 Bs[2 * 128 * 32];
    const int K = 512;
    const int tid = threadIdx.x, wave = tid >> 6, lane = tid & 63;
    const int l15 = lane & 15, quad = lane >> 4;
    const int bm = blockIdx.x * 128, bn = blockIdx.y * 128;
    const bool vmode = (bn >= 1024);
    const int wr = wave >> 1, wc = wave & 1;
    const int arow = lane >> 2;
    const int acol = (lane & 3) * 8;

    f32x4 acc[4][4] = {};
#pragma unroll
    for (int ii = 0; ii < 2; ii++) {
        const int inst = wave * 2 + ii;
        const int row = inst * 16 + arow;
        load_lds16(&X[(bm + row) * K + acol], &As[inst * 512]);
        load_lds16(&W[(bn + row) * K + acol], &Bs[inst * 512]);
    }
    int cur = 0;
    for (int k0 = 0; k0 < K; k0 += 32) {
        __builtin_amdgcn_s_barrier();
        if (k0 + 32 < K) {
            const int nb = (cur ^ 1) * 4096;
#pragma unroll
            for (int ii = 0; ii < 2; ii++) {
                const int inst = wave * 2 + ii;
                const int row = inst * 16 + arow;
                load_lds16(&X[(bm + row) * K + k0 + 32 + acol], &As[nb + inst * 512]);
                load_lds16(&W[(bn + row) * K + k0 + 32 + acol], &Bs[nb + inst * 512]);
            }
            asm volatile("s_waitcnt vmcnt(4)" ::: "memory");
        } else {
            asm volatile("s_waitcnt vmcnt(0)" ::: "memory");
        }
        __builtin_amdgcn_s_barrier();
        const int cb = cur * 4096;
        bf16x8 a[4], b[4];
#pragma unroll
        for (int i = 0; i < 4; i++)
            a[i] = *(const bf16x8*)&As[cb + (wr * 64 + i * 16 + l15) * 32 + quad * 8];
#pragma unroll
        for (int j = 0; j < 4; j++)
            b[j] = *(const bf16x8*)&Bs[cb + (wc * 64 + j * 16 + l15) * 32 + quad * 8];
        if (vmode) {
#pragma unroll
            for (int i = 0; i < 4; i++)
#pragma unroll
                for (int j = 0; j < 4; j++)
                    acc[i][j] = MFMA(a[j], b[i], acc[i][j]);
        } else {
#pragma unroll
            for (int i = 0; i < 4; i++)
#pragma unroll
                for (int j = 0; j < 4; j++)
                    acc[i][j] = MFMA(b[i], a[j], acc[i][j]);
        }
        cur ^= 1;
    }

    const int nbase = bn + wc * 64;
    if (vmode) {
#pragma unroll
        for (int i = 0; i < 4; i++) {
            const int d0 = nbase + i * 16 + l15;
            const float bvf = bias[d0];
            const int d0m = d0 & 511;
            const int h = d0m >> 6, hd0 = d0m & 63;
            const int n = hd0 >> 4, lv = hd0 & 15;
#pragma unroll
            for (int j = 0; j < 4; j++) {
                const int s_g = bm + wr * 64 + j * 16 + quad * 4;
                const int b_ = s_g >> 12, s0 = s_g & 4095;
                const int kt = s0 >> 6, kk = s0 & 63;
                const int half = kk >> 5, qv = (kk >> 3) & 3, e0 = kk & 7;
                ushort4 pk;
                pk.x = f2bf(acc[i][j][0] + bvf);
                pk.y = f2bf(acc[i][j][1] + bvf);
                pk.z = f2bf(acc[i][j][2] + bvf);
                pk.w = f2bf(acc[i][j][3] + bvf);
                const size_t off = ((size_t)((b_ * 8 + h) * 64 + kt)) * 4096 +
                                   n * 1024 + half * 512 + qv * 128 + lv * 8 + e0;
                *(ushort4*)&Vf[off] = pk;
            }
        }
    } else {
        const int which = nbase >> 9;  // 0=q 1=k
#pragma unroll
        for (int i = 0; i < 4; i++) {
            const int d0 = nbase + i * 16 + quad * 4;
            const float4 bv = *(const float4*)&bias[d0];
            const int d0m = d0 & 511;
            const int h = d0m >> 6, hd0 = d0m & 63;
#pragma unroll
            for (int j = 0; j < 4; j++) {
                const int s_g = bm + wr * 64 + j * 16 + l15;
                const int b_ = s_g >> 12, s0 = s_g & 4095;
                const int bhh = b_ * 8 + h;
                const int kt = s0 >> 6;
                if (which == 1) {
                    const int jj = (s0 >> 4) & 3, lr = s0 & 15;
                    const int half = hd0 >> 5, q4 = (hd0 >> 3) & 3, e0 = hd0 & 7;
                    ushort4 pk;
                    pk.x = f2bf(acc[i][j][0] + bv.x);
                    pk.y = f2bf(acc[i][j][1] + bv.y);
                    pk.z = f2bf(acc[i][j][2] + bv.z);
                    pk.w = f2bf(acc[i][j][3] + bv.w);
                    const size_t off = ((size_t)(bhh * 64 + kt)) * 4096 +
                                       jj * 1024 + half * 512 + q4 * 128 + lr * 8 + e0;
                    *(ushort4*)&Kf[off] = pk;
                } else {
                    ushort4 pk;
                    pk.x = f2bf((acc[i][j][0] + bv.x) * QSCALE);
                    pk.y = f2bf((acc[i][j][1] + bv.y) * QSCALE);
                    pk.z = f2bf((acc[i][j][2] + bv.z) * QSCALE);
                    pk.w = f2bf((acc[i][j][3] + bv.w) * QSCALE);
                    *(ushort4*)&QY[((b_ * 4096 + s0) * 8 + h) * 64 + hd0] = pk;
                }
            }
        }
    }
}

// ---------------------------------------------------------------------------
// Fused split-K flash attention + merge, ZERO-MAX softmax (r10 topology).
// Block = 2 waves (wave = k-half), q-tile pair {p, 255-p} of 16-ROW tiles:
// nt(p)=(p>>2)+1, pair total = 65 k-tiles always. Grid (16, 128): x = bh,
// y = p. 4096 waves -> 4/SIMD. Single Q-frag (16 rows) per wave.
// Per tile: LOADV(kt)+LOADK(kt+1) up-front (volatile asm); WAITV(16) before
// QK; WAITV(8) before PV; never drains mid-loop (constants re-verified for
// the 2-GLD Q prologue). Phase end: wave1 -> LDS (o,l); __syncthreads;
// wave0 sums, normalizes, writes Y into QY in place.
// ---------------------------------------------------------------------------
#define LS 72

#define GLD(dst, base, OFF)                                                  \
    asm volatile("global_load_dwordx4 %0, %1, off offset:" #OFF              \
                 : "=v"(dst) : "v"(base))

#define WAITV(N) do {                                                        \
    asm volatile("s_waitcnt vmcnt(" #N ")" ::: "memory");                    \
    __builtin_amdgcn_sched_barrier(0);                                       \
} while (0)

__global__ __launch_bounds__(128, 2) void attn_k(
    u16* __restrict__ QY, const u16* __restrict__ Kf, const u16* __restrict__ Vf)
{
    __shared__ u16 Ps[2 * 16 * LS];     // per-wave P staging (4.5 KiB)
    __shared__ float OxA[4][64][4];     // wave1 -> wave0 o exchange
    __shared__ float Lx[64];            // wave1 l

    const int tid = threadIdx.x;
    const int wave = tid >> 6, lane = tid & 63;
    const int l15 = lane & 15, quad = lane >> 4;
    const int bh = blockIdx.x;
    const int b_ = bh >> 3, h = bh & 7;
    const int p = (int)blockIdx.y;
    const int seg = wave;

    bf16x8 ones;
#pragma unroll
    for (int i = 0; i < 8; i++) ones[i] = (__bf16)1.0f;

    const u16* KfB = &Kf[((size_t)bh * 64) * 4096 + lane * 8];
    const u16* VfB = &Vf[((size_t)bh * 64) * 4096 + lane * 8];
    u16* P = &Ps[wave * 16 * LS];

#define LOADK(DK, KT) do {                                                   \
    const u16* ka_ = KfB + (size_t)(KT) * 4096;                              \
    const u16* kb_ = ka_ + 2048;                                             \
    GLD(DK[0][0], ka_, 0);    GLD(DK[0][1], ka_, 1024);                      \
    GLD(DK[1][0], ka_, 2048); GLD(DK[1][1], ka_, 3072);                      \
    GLD(DK[2][0], kb_, 0);    GLD(DK[2][1], kb_, 1024);                      \
    GLD(DK[3][0], kb_, 2048); GLD(DK[3][1], kb_, 3072);                      \
} while (0)

#define LOADV(DV, KT) do {                                                   \
    const u16* va_ = VfB + (size_t)(KT) * 4096;                              \
    const u16* vb_ = va_ + 2048;                                             \
    GLD(DV[0][0], va_, 0);    GLD(DV[0][1], va_, 1024);                      \
    GLD(DV[1][0], va_, 2048); GLD(DV[1][1], va_, 3072);                      \
    GLD(DV[2][0], vb_, 0);    GLD(DV[2][1], vb_, 1024);                      \
    GLD(DV[3][0], vb_, 2048); GLD(DV[3][1], vb_, 3072);                      \
} while (0)

// QK single frag + softmax + P round-trip (needs K regs; V may be in flight)
#define TILE_A(KC, KT) do {                                                  \
    const int k0_ = (KT) * 64;                                               \
    const bool nmA_ = (k0_ + 63 > base_r);                                   \
    f32x4 sa_[4];                                                            \
    _Pragma("unroll")                                                        \
    for (int j_ = 0; j_ < 4; j_++) {                                         \
        f32x4 ia_ = {};                                                      \
        if (nmA_) {                                                          \
            _Pragma("unroll")                                                \
            for (int r_ = 0; r_ < 4; r_++) {                                 \
                const int key_ = k0_ + j_ * 16 + quad * 4 + r_;              \
                ia_[r_] = (key_ > rowA) ? -1e30f : 0.0f;                     \
            }                                                                \
        }                                                                    \
        ia_ = MFMA(KC[j_][0], qa0, ia_);                                     \
        sa_[j_] = MFMA(KC[j_][1], qa1, ia_);                                 \
    }                                                                        \
    _Pragma("unroll")                                                        \
    for (int j_ = 0; j_ < 4; j_++) {                                         \
        ushort4 w_;                                                          \
        w_.x = f2bf(exp2_fast(sa_[j_][0]));                                  \
        w_.y = f2bf(exp2_fast(sa_[j_][1]));                                  \
        w_.z = f2bf(exp2_fast(sa_[j_][2]));                                  \
        w_.w = f2bf(exp2_fast(sa_[j_][3]));                                  \
        *(ushort4*)&P[l15 * LS + j_ * 16 + quad * 4] = w_;                   \
    }                                                                        \
    pfa0 = *(const bf16x8*)&P[l15 * LS + quad * 8];                          \
    pfa1 = *(const bf16x8*)&P[l15 * LS + 32 + quad * 8];                     \
} while (0)

// PV single frag (needs V regs; pfa persisted from TILE_A)
#define TILE_B(VC) do {                                                      \
    lacc_a = MFMA(ones, pfa0, lacc_a);                                       \
    lacc_a = MFMA(ones, pfa1, lacc_a);                                       \
    _Pragma("unroll")                                                        \
    for (int n_ = 0; n_ < 4; n_++) {                                         \
        oa[n_] = MFMA(VC[n_][0], pfa0, oa[n_]);                              \
        oa[n_] = MFMA(VC[n_][1], pfa1, oa[n_]);                              \
    }                                                                        \
} while (0)

    for (int phase = 0; phase < 2; phase++) {
        const int qt16 = phase ? (255 - p) : p;
        const int nt = (qt16 >> 2) + 1;
        const int hlf = (nt + 1) >> 1;
        const int t0 = seg ? hlf : 0;
        const int t1 = seg ? nt : hlf;
        const int base_r = qt16 * 16;

        f32x4 oa[4] = {};
        f32x4 lacc_a = {};
        const int rowA = base_r + l15;

        if (t0 < t1) {
            const u16* qpa = &QY[((b_ * 4096 + base_r + l15) * 8 + h) * 64 + quad * 8];
            bf16x8 qa0, qa1;
            GLD(qa0, qpa, 0);
            GLD(qa1, qpa, 64);

            bf16x8 pfa0, pfa1;
            bf16x8 kR[4][2], kS[4][2], vv[4][2];

            LOADK(kR, t0);
            for (int kt = t0; kt < t1; kt += 2) {
                const bool h1 = (kt + 1 < t1);
                LOADV(vv, kt);
                if (h1) LOADK(kS, kt + 1);
                if (h1) { WAITV(16); } else { WAITV(8); }
                TILE_A(kR, kt);
                if (h1) { WAITV(8); } else { WAITV(0); }
                TILE_B(vv);
                if (h1) {
                    const bool h2 = (kt + 2 < t1);
                    LOADV(vv, kt + 1);
                    if (h2) LOADK(kR, kt + 2);
                    if (h2) { WAITV(16); } else { WAITV(8); }
                    TILE_A(kS, kt + 1);
                    if (h2) { WAITV(8); } else { WAITV(0); }
                    TILE_B(vv);
                }
            }
            WAITV(0);
        }

        // ---- fused merge (r10-verified topology) ----
        if (wave == 1) {
#pragma unroll
            for (int n = 0; n < 4; n++)
                *(f32x4*)&OxA[n][lane][0] = oa[n];
            Lx[lane] = lacc_a[0];
        }
        __syncthreads();
        if (wave == 0) {
            const float la = lacc_a[0] + Lx[lane];
            const float iva = (la > 0.0f) ? 1.0f / la : 0.0f;
            u16* ya = &QY[((size_t)((b_ * 4096 + base_r + l15) * 8 + h)) * 64];
#pragma unroll
            for (int n = 0; n < 4; n++) {
                f32x4 s0 = *(const f32x4*)&OxA[n][lane][0];
                ushort4 wa;
                wa.x = f2bf((oa[n][0] + s0[0]) * iva);
                wa.y = f2bf((oa[n][1] + s0[1]) * iva);
                wa.z = f2bf((oa[n][2] + s0[2]) * iva);
                wa.w = f2bf((oa[n][3] + s0[3]) * iva);
                *(ushort4*)&ya[n * 16 + quad * 4] = wa;
            }
        }
        __syncthreads();
    }
#undef LOADK
#undef LOADV
#undef TILE_A
#undef TILE_B
}

// ---------------------------------------------------------------------------
// GEMM3: out = y @ Wo^T + bo, operand-swapped -> float4 stores.
// Same dbuf + counted-vmcnt K-loop as GEMM1.
// ---------------------------------------------------------------------------
__global__ __launch_bounds__(256) void gemm_o_bf(
    const u16* __restrict__ X, const u16* __restrict__ W,
    const float* __restrict__ bias, float* __restrict__ Out)
{
    __shared__ u16 As[2 * 128 * 32];
    __shared__ u16 Bs[2 * 128 * 32];
    const int K = 512;
    const int tid = threadIdx.x, wave = tid >> 6, lane = tid & 63;
    const int l15 = lane & 15, quad = lane >> 4;
    const int bm = blockIdx.x * 128, bn = blockIdx.y * 128;
    const int wr = wave >> 1, wc = wave & 1;
    const int arow = lane >> 2;
    const int acol = (lane & 3) * 8;

    f32x4 acc[4][4] = {};
#pragma unroll
    for (int ii = 0; ii < 2; ii++) {
        const int inst = wave * 2 + ii;
        const int row = inst * 16 + arow;
        load_lds16(&X[(bm + row) * K + acol], &As[inst * 512]);
        load_lds16(&W[(bn + row) * K + acol], &Bs[inst * 512]);
    }
    int cur = 0;
    for (int k0 = 0; k0 < K; k0 += 32) {
        __builtin_amdgcn_s_barrier();
        if (k0 + 32 < K) {
            const int nb = (cur ^ 1) * 4096;
#pragma unroll
            for (int ii = 0; ii < 2; ii++) {
                const int inst = wave * 2 + ii;
                const int row = inst * 16 + arow;
                load_lds16(&X[(bm + row) * K + k0 + 32 + acol], &As[nb + inst * 512]);
                load_lds16(&W[(bn + row) * K + k0 + 32 + acol], &Bs[nb + inst * 512]);
            }
            asm volatile("s_waitcnt vmcnt(4)" ::: "memory");
        } else {
            asm volatile("s_waitcnt vmcnt(0)" ::: "memory");
        }
        __builtin_amdgcn_s_barrier();
        const int cb = cur * 4096;
        bf16x8 a[4], b[4];
#pragma unroll
        for (int i = 0; i < 4; i++)
            a[i] = *(const bf16x8*)&As[cb + (wr * 64 + i * 16 + l15) * 32 + quad * 8];
#pragma unroll
        for (int j = 0; j < 4; j++)
            b[j] = *(const bf16x8*)&Bs[cb + (wc * 64 + j * 16 + l15) * 32 + quad * 8];
#pragma unroll
        for (int i = 0; i < 4; i++)
#pragma unroll
            for (int j = 0; j < 4; j++)
                acc[i][j] = MFMA(b[i], a[j], acc[i][j]);
        cur ^= 1;
    }
#pragma unroll
    for (int i = 0; i < 4; i++) {
        const int n0 = bn + wc * 64 + i * 16 + quad * 4;
        const float4 bv = *(const float4*)&bias[n0];
#pragma unroll
        for (int j = 0; j < 4; j++) {
            const int m = bm + wr * 64 + j * 16 + l15;
            float4 ov;
            ov.x = acc[i][j][0] + bv.x;
            ov.y = acc[i][j][1] + bv.y;
            ov.z = acc[i][j][2] + bv.z;
            ov.w = acc[i][j][3] + bv.w;
            *(float4*)&Out[(size_t)m * 512 + n0] = ov;
        }
    }
}

extern "C" void kernel_launch(void* const* d_in, const int* in_sizes, int n_in,
                              void* d_out, int out_size, void* d_ws, size_t ws_size,
                              hipStream_t stream) {
    (void)in_sizes; (void)n_in; (void)out_size; (void)ws_size;
    const float* x    = (const float*)d_in[0];
    const float* Wqkv = (const float*)d_in[1];
    const float* bqkv = (const float*)d_in[2];
    const float* Wo   = (const float*)d_in[3];
    const float* bo   = (const float*)d_in[4];
    float* out = (float*)d_out;

    u16* qy_ws = (u16*)d_ws;                 // 8 MiB  [b][s][h][hd] (Q -> Y in place)
    u16* kf_ws = qy_ws + 4194304;            // 8 MiB  Kf frag-major
    u16* vf_ws = kf_ws + 4194304;            // 8 MiB  Vf frag-major
    float* ml  = (float*)(vf_ws + 4194304);  // 1 MiB region (unused, kept for layout)
    u16* wqkvb = (u16*)(ml + 262144);        // 1.5 MiB bf16 Wqkv
    u16* wob   = wqkvb + 786432;             // 0.5 MiB bf16 Wo
    u16* xb    = (u16*)d_out;                // 8 MiB bf16 x (dead after gemm1)

    cvt_all<<<5120, 256, 0, stream>>>(x, Wqkv, Wo, xb, wqkvb, wob);
    gemm_qkv_bf<<<dim3(64, 12), 256, 0, stream>>>(xb, wqkvb, bqkv, qy_ws, kf_ws, vf_ws);
    attn_k<<<dim3(16, 128), 128, 0, stream>>>(qy_ws, kf_ws, vf_ws);
    gemm_o_bf<<<dim3(64, 4), 256, 0, stream>>>(qy_ws, wob, bo, out);
}

// Round 15
// 173.418 us; speedup vs baseline: 1.1299x; 1.1299x over previous
//
#include <hip/hip_runtime.h>

// B=2, S=4096, D=512, H=8, HD=64. fp32 in/out; bf16 MFMA internally.
// ws (27 MiB): qy[2][4096][8][64] (Q, then Y in-place) | Kf frag-major |
//              Vf frag-major | (unused) | wqkvb bf16 | wob bf16
// d_out (16 MiB): xb bf16 scratch (dead after gemm1), then fp32 out.
// attn uses ZERO-MAX softmax in exp2 domain: p = exp2(s); o and l scale
// together (ratio invariant).
// r15 = r10 byte-for-byte (best verified fused config, 175us total, attn 62).
// r11-r14 post-mortem: 4-wave merge NaN'd 3x (topology abandoned); 16-row
// tiles regressed 44% (issue-bound: per-tile fixed cost dominates; occupancy
// pinned ~17% regardless of grid => residency cap not movable by grid).
// Structure: merge fused into attn (4 kernels), block = 2 waves (wave=seg)
// on q-tile pair {p,127-p} = 65 tiles/block; asm GLD + counted-vmcnt ladder
// (vmcnt(16) before QK, vmcnt(8) before PV, no mid-loop drains); wave1 ->
// LDS (o,l), wave0 sums+normalizes+writes Y in-place (row-exclusive).

typedef __bf16 bf16x8 __attribute__((ext_vector_type(8)));
typedef float f32x4 __attribute__((ext_vector_type(4)));
typedef unsigned short u16;

#define MFMA(a, b, c) __builtin_amdgcn_mfma_f32_16x16x32_bf16(a, b, c, 0, 0, 0)
#define QSCALE 0.18033688011112042f   // 1/sqrt(64) * log2(e)

__device__ __forceinline__ float exp2_fast(float x) {
    return __builtin_amdgcn_exp2f(x);
}
__device__ __forceinline__ u16 f2bf(float f) {
    union { __bf16 h; u16 u; } v; v.h = (__bf16)f; return v.u;
}
__device__ __forceinline__ ushort4 f4_to_bf4(float4 v) {
    ushort4 r;
    r.x = f2bf(v.x); r.y = f2bf(v.y); r.z = f2bf(v.z); r.w = f2bf(v.w);
    return r;
}
__device__ __forceinline__ void load_lds16(const u16* g, u16* l) {
    __builtin_amdgcn_global_load_lds(
        (const __attribute__((address_space(1))) void*)g,
        (__attribute__((address_space(3))) void*)l, 16, 0, 0);
}

// ---------------------------------------------------------------------------
// One fused fp32->bf16 convert for x, Wqkv, Wo
// ---------------------------------------------------------------------------
__global__ __launch_bounds__(256) void cvt_all(
    const float* __restrict__ x, const float* __restrict__ wq,
    const float* __restrict__ wo,
    u16* __restrict__ xb, u16* __restrict__ wqb, u16* __restrict__ wob)
{
    int i = blockIdx.x * 256 + threadIdx.x;
    if (i < 1048576) {
        ((ushort4*)xb)[i] = f4_to_bf4(((const float4*)x)[i]);
    } else if (i < 1048576 + 196608) {
        int j = i - 1048576;
        ((ushort4*)wqb)[j] = f4_to_bf4(((const float4*)wq)[j]);
    } else {
        int j = i - 1048576 - 196608;
        ((ushort4*)wob)[j] = f4_to_bf4(((const float4*)wo)[j]);
    }
}

// ---------------------------------------------------------------------------
// GEMM1: qkv = x @ Wqkv^T + b. Q/K blocks: operand-swapped (C^T) epilogue.
// V blocks (bn>=1024): NON-swapped MFMA -> C rows = s (r-contiguous), cols = d
// -> Vf fragment write is 16 aligned ushort4 stores.
// ---------------------------------------------------------------------------
__global__ __launch_bounds__(256) void gemm_qkv_bf(
    const u16* __restrict__ X, const u16* __restrict__ W,
    const float* __restrict__ bias,
    u16* __restrict__ QY, u16* __restrict__ Kf, u16* __restrict__ Vf)
{
    __shared__ u16 As[2 * 128 * 32];
    __shared__ u16 Bs[2 * 128 * 32];
    const int K = 512;
    const int tid = threadIdx.x, wave = tid >> 6, lane = tid & 63;
    const int l15 = lane & 15, quad = lane >> 4;
    const int bm = blockIdx.x * 128, bn = blockIdx.y * 128;
    const bool vmode = (bn >= 1024);
    const int wr = wave >> 1, wc = wave & 1;
    const int arow = lane >> 2;
    const int acol = (lane & 3) * 8;

    f32x4 acc[4][4] = {};
#pragma unroll
    for (int ii = 0; ii < 2; ii++) {
        const int inst = wave * 2 + ii;
        const int row = inst * 16 + arow;
        load_lds16(&X[(bm + row) * K + acol], &As[inst * 512]);
        load_lds16(&W[(bn + row) * K + acol], &Bs[inst * 512]);
    }
    int cur = 0;
    for (int k0 = 0; k0 < K; k0 += 32) {
        __builtin_amdgcn_s_barrier();
        if (k0 + 32 < K) {
            const int nb = (cur ^ 1) * 4096;
#pragma unroll
            for (int ii = 0; ii < 2; ii++) {
                const int inst = wave * 2 + ii;
                const int row = inst * 16 + arow;
                load_lds16(&X[(bm + row) * K + k0 + 32 + acol], &As[nb + inst * 512]);
                load_lds16(&W[(bn + row) * K + k0 + 32 + acol], &Bs[nb + inst * 512]);
            }
            asm volatile("s_waitcnt vmcnt(4)" ::: "memory");
        } else {
            asm volatile("s_waitcnt vmcnt(0)" ::: "memory");
        }
        __builtin_amdgcn_s_barrier();
        const int cb = cur * 4096;
        bf16x8 a[4], b[4];
#pragma unroll
        for (int i = 0; i < 4; i++)
            a[i] = *(const bf16x8*)&As[cb + (wr * 64 + i * 16 + l15) * 32 + quad * 8];
#pragma unroll
        for (int j = 0; j < 4; j++)
            b[j] = *(const bf16x8*)&Bs[cb + (wc * 64 + j * 16 + l15) * 32 + quad * 8];
        if (vmode) {
#pragma unroll
            for (int i = 0; i < 4; i++)
#pragma unroll
                for (int j = 0; j < 4; j++)
                    acc[i][j] = MFMA(a[j], b[i], acc[i][j]);
        } else {
#pragma unroll
            for (int i = 0; i < 4; i++)
#pragma unroll
                for (int j = 0; j < 4; j++)
                    acc[i][j] = MFMA(b[i], a[j], acc[i][j]);
        }
        cur ^= 1;
    }

    const int nbase = bn + wc * 64;
    if (vmode) {
#pragma unroll
        for (int i = 0; i < 4; i++) {
            const int d0 = nbase + i * 16 + l15;
            const float bvf = bias[d0];
            const int d0m = d0 & 511;
            const int h = d0m >> 6, hd0 = d0m & 63;
            const int n = hd0 >> 4, lv = hd0 & 15;
#pragma unroll
            for (int j = 0; j < 4; j++) {
                const int s_g = bm + wr * 64 + j * 16 + quad * 4;
                const int b_ = s_g >> 12, s0 = s_g & 4095;
                const int kt = s0 >> 6, kk = s0 & 63;
                const int half = kk >> 5, qv = (kk >> 3) & 3, e0 = kk & 7;
                ushort4 pk;
                pk.x = f2bf(acc[i][j][0] + bvf);
                pk.y = f2bf(acc[i][j][1] + bvf);
                pk.z = f2bf(acc[i][j][2] + bvf);
                pk.w = f2bf(acc[i][j][3] + bvf);
                const size_t off = ((size_t)((b_ * 8 + h) * 64 + kt)) * 4096 +
                                   n * 1024 + half * 512 + qv * 128 + lv * 8 + e0;
                *(ushort4*)&Vf[off] = pk;
            }
        }
    } else {
        const int which = nbase >> 9;  // 0=q 1=k
#pragma unroll
        for (int i = 0; i < 4; i++) {
            const int d0 = nbase + i * 16 + quad * 4;
            const float4 bv = *(const float4*)&bias[d0];
            const int d0m = d0 & 511;
            const int h = d0m >> 6, hd0 = d0m & 63;
#pragma unroll
            for (int j = 0; j < 4; j++) {
                const int s_g = bm + wr * 64 + j * 16 + l15;
                const int b_ = s_g >> 12, s0 = s_g & 4095;
                const int bhh = b_ * 8 + h;
                const int kt = s0 >> 6;
                if (which == 1) {
                    const int jj = (s0 >> 4) & 3, lr = s0 & 15;
                    const int half = hd0 >> 5, q4 = (hd0 >> 3) & 3, e0 = hd0 & 7;
                    ushort4 pk;
                    pk.x = f2bf(acc[i][j][0] + bv.x);
                    pk.y = f2bf(acc[i][j][1] + bv.y);
                    pk.z = f2bf(acc[i][j][2] + bv.z);
                    pk.w = f2bf(acc[i][j][3] + bv.w);
                    const size_t off = ((size_t)(bhh * 64 + kt)) * 4096 +
                                       jj * 1024 + half * 512 + q4 * 128 + lr * 8 + e0;
                    *(ushort4*)&Kf[off] = pk;
                } else {
                    ushort4 pk;
                    pk.x = f2bf((acc[i][j][0] + bv.x) * QSCALE);
                    pk.y = f2bf((acc[i][j][1] + bv.y) * QSCALE);
                    pk.z = f2bf((acc[i][j][2] + bv.z) * QSCALE);
                    pk.w = f2bf((acc[i][j][3] + bv.w) * QSCALE);
                    *(ushort4*)&QY[((b_ * 4096 + s0) * 8 + h) * 64 + hd0] = pk;
                }
            }
        }
    }
}

// ---------------------------------------------------------------------------
// Fused split-K flash attention + merge, ZERO-MAX softmax, asm-pinned pipeline.
// Block = 2 waves (wave = seg), q-tile pair {p, 127-p}: 65 tiles/block, all
// blocks identical. Grid (16, 64): x = bh, y = p.
// Per tile (per wave): LOADV(kt)+LOADK(kt+1) up-front (volatile asm);
// vmcnt(16) gate before QK; vmcnt(8) before PV; never drains mid-loop.
// Phase end: wave1 -> LDS (o,l); __syncthreads; wave0 sums, normalizes,
// writes Y into QY in place (rows owned exclusively by this block).
// ---------------------------------------------------------------------------
#define LS 72

#define GLD(dst, base, OFF)                                                  \
    asm volatile("global_load_dwordx4 %0, %1, off offset:" #OFF              \
                 : "=v"(dst) : "v"(base))

#define WAITV(N) do {                                                        \
    asm volatile("s_waitcnt vmcnt(" #N ")" ::: "memory");                    \
    __builtin_amdgcn_sched_barrier(0);                                       \
} while (0)

__global__ __launch_bounds__(128, 2) void attn_k(
    u16* __restrict__ QY, const u16* __restrict__ Kf, const u16* __restrict__ Vf)
{
    __shared__ u16 Ps[2 * 16 * LS];     // per-wave P staging
    __shared__ float OxA[4][64][4];     // wave1 -> wave0 o exchange (frag A)
    __shared__ float OxB[4][64][4];     // frag B
    __shared__ float Lx[64][2];         // wave1 l_a, l_b

    const int tid = threadIdx.x;
    const int wave = tid >> 6, lane = tid & 63;
    const int l15 = lane & 15, quad = lane >> 4;
    const int bh = blockIdx.x;
    const int b_ = bh >> 3, h = bh & 7;
    const int p = (int)blockIdx.y;
    const int seg = wave;

    bf16x8 ones;
#pragma unroll
    for (int i = 0; i < 8; i++) ones[i] = (__bf16)1.0f;

    const u16* KfB = &Kf[((size_t)bh * 64) * 4096 + lane * 8];
    const u16* VfB = &Vf[((size_t)bh * 64) * 4096 + lane * 8];
    u16* P = &Ps[wave * 16 * LS];

#define LOADK(DK, KT) do {                                                   \
    const u16* ka_ = KfB + (size_t)(KT) * 4096;                              \
    const u16* kb_ = ka_ + 2048;                                             \
    GLD(DK[0][0], ka_, 0);    GLD(DK[0][1], ka_, 1024);                      \
    GLD(DK[1][0], ka_, 2048); GLD(DK[1][1], ka_, 3072);                      \
    GLD(DK[2][0], kb_, 0);    GLD(DK[2][1], kb_, 1024);                      \
    GLD(DK[3][0], kb_, 2048); GLD(DK[3][1], kb_, 3072);                      \
} while (0)

#define LOADV(DV, KT) do {                                                   \
    const u16* va_ = VfB + (size_t)(KT) * 4096;                              \
    const u16* vb_ = va_ + 2048;                                             \
    GLD(DV[0][0], va_, 0);    GLD(DV[0][1], va_, 1024);                      \
    GLD(DV[1][0], va_, 2048); GLD(DV[1][1], va_, 3072);                      \
    GLD(DV[2][0], vb_, 0);    GLD(DV[2][1], vb_, 1024);                      \
    GLD(DV[3][0], vb_, 2048); GLD(DV[3][1], vb_, 3072);                      \
} while (0)

#define TILE_A(KC, KT) do {                                                  \
    const int k0_ = (KT) * 64;                                               \
    const bool nmA_ = (k0_ + 63 > base_r);                                   \
    const bool nmB_ = (k0_ + 63 > base_r + 16);                              \
    f32x4 sa_[4], sb_[4];                                                    \
    _Pragma("unroll")                                                        \
    for (int j_ = 0; j_ < 4; j_++) {                                         \
        f32x4 ia_ = {}, ib_ = {};                                            \
        if (nmA_) {                                                          \
            _Pragma("unroll")                                                \
            for (int r_ = 0; r_ < 4; r_++) {                                 \
                const int key_ = k0_ + j_ * 16 + quad * 4 + r_;              \
                ia_[r_] = (key_ > rowA) ? -1e30f : 0.0f;                     \
            }                                                                \
        }                                                                    \
        if (nmB_) {                                                          \
            _Pragma("unroll")                                                \
            for (int r_ = 0; r_ < 4; r_++) {                                 \
                const int key_ = k0_ + j_ * 16 + quad * 4 + r_;              \
                ib_[r_] = (key_ > rowA + 16) ? -1e30f : 0.0f;                \
            }                                                                \
        }                                                                    \
        ia_ = MFMA(KC[j_][0], qa0, ia_);                                     \
        sa_[j_] = MFMA(KC[j_][1], qa1, ia_);                                 \
        ib_ = MFMA(KC[j_][0], qb0, ib_);                                     \
        sb_[j_] = MFMA(KC[j_][1], qb1, ib_);                                 \
    }                                                                        \
    _Pragma("unroll")                                                        \
    for (int j_ = 0; j_ < 4; j_++) {                                         \
        ushort4 w_;                                                          \
        w_.x = f2bf(exp2_fast(sa_[j_][0]));                                  \
        w_.y = f2bf(exp2_fast(sa_[j_][1]));                                  \
        w_.z = f2bf(exp2_fast(sa_[j_][2]));                                  \
        w_.w = f2bf(exp2_fast(sa_[j_][3]));                                  \
        *(ushort4*)&P[l15 * LS + j_ * 16 + quad * 4] = w_;                   \
    }                                                                        \
    _Pragma("unroll")                                                        \
    for (int j_ = 0; j_ < 4; j_++)                                           \
        _Pragma("unroll")                                                    \
        for (int r_ = 0; r_ < 4; r_++)                                       \
            spb[j_][r_] = exp2_fast(sb_[j_][r_]);                            \
    pfa0 = *(const bf16x8*)&P[l15 * LS + quad * 8];                          \
    pfa1 = *(const bf16x8*)&P[l15 * LS + 32 + quad * 8];                     \
    _Pragma("unroll")                                                        \
    for (int j_ = 0; j_ < 4; j_++) {                                         \
        ushort4 w_;                                                          \
        w_.x = f2bf(spb[j_][0]); w_.y = f2bf(spb[j_][1]);                    \
        w_.z = f2bf(spb[j_][2]); w_.w = f2bf(spb[j_][3]);                    \
        *(ushort4*)&P[l15 * LS + j_ * 16 + quad * 4] = w_;                   \
    }                                                                        \
} while (0)

#define TILE_B(VC) do {                                                      \
    lacc_a = MFMA(ones, pfa0, lacc_a);                                       \
    lacc_a = MFMA(ones, pfa1, lacc_a);                                       \
    _Pragma("unroll")                                                        \
    for (int n_ = 0; n_ < 4; n_++) {                                         \
        oa[n_] = MFMA(VC[n_][0], pfa0, oa[n_]);                              \
        oa[n_] = MFMA(VC[n_][1], pfa1, oa[n_]);                              \
    }                                                                        \
    bf16x8 pfb0_ = *(const bf16x8*)&P[l15 * LS + quad * 8];                  \
    bf16x8 pfb1_ = *(const bf16x8*)&P[l15 * LS + 32 + quad * 8];             \
    lacc_b = MFMA(ones, pfb0_, lacc_b);                                      \
    lacc_b = MFMA(ones, pfb1_, lacc_b);                                      \
    _Pragma("unroll")                                                        \
    for (int n_ = 0; n_ < 4; n_++) {                                         \
        ob[n_] = MFMA(VC[n_][0], pfb0_, ob[n_]);                             \
        ob[n_] = MFMA(VC[n_][1], pfb1_, ob[n_]);                             \
    }                                                                        \
} while (0)

    for (int phase = 0; phase < 2; phase++) {
        const int qt32 = phase ? (127 - p) : p;
        const int nt = (qt32 >> 1) + 1;
        const int hlf = (nt + 1) >> 1;
        const int t0 = seg ? hlf : 0;
        const int t1 = seg ? nt : hlf;
        const int base_r = qt32 * 32;

        const u16* qpa = &QY[((b_ * 4096 + base_r + l15) * 8 + h) * 64 + quad * 8];
        const u16* qpb = qpa + 16 * 8 * 64;
        bf16x8 qa0, qa1, qb0, qb1;
        GLD(qa0, qpa, 0);
        GLD(qa1, qpa, 64);
        GLD(qb0, qpb, 0);
        GLD(qb1, qpb, 64);

        f32x4 oa[4] = {}, ob[4] = {};
        f32x4 lacc_a = {}, lacc_b = {};
        const int rowA = base_r + l15;

        float spb[4][4];
        bf16x8 pfa0, pfa1;
        bf16x8 kR[4][2], kS[4][2], vv[4][2];

        if (t0 < t1) LOADK(kR, t0);
        for (int kt = t0; kt < t1; kt += 2) {
            const bool h1 = (kt + 1 < t1);
            LOADV(vv, kt);
            if (h1) LOADK(kS, kt + 1);
            if (h1) { WAITV(16); } else { WAITV(8); }
            TILE_A(kR, kt);
            if (h1) { WAITV(8); } else { WAITV(0); }
            TILE_B(vv);
            if (h1) {
                const bool h2 = (kt + 2 < t1);
                LOADV(vv, kt + 1);
                if (h2) LOADK(kR, kt + 2);
                if (h2) { WAITV(16); } else { WAITV(8); }
                TILE_A(kS, kt + 1);
                if (h2) { WAITV(8); } else { WAITV(0); }
                TILE_B(vv);
            }
        }

        // ---- fused merge: wave1 -> LDS; wave0 sums, normalizes, writes Y ----
        if (wave == 1) {
#pragma unroll
            for (int n = 0; n < 4; n++) {
                *(f32x4*)&OxA[n][lane][0] = oa[n];
                *(f32x4*)&OxB[n][lane][0] = ob[n];
            }
            Lx[lane][0] = lacc_a[0];
            Lx[lane][1] = lacc_b[0];
        }
        __syncthreads();
        if (wave == 0) {
            const float la = lacc_a[0] + Lx[lane][0];
            const float lb = lacc_b[0] + Lx[lane][1];
            const float iva = (la > 0.0f) ? 1.0f / la : 0.0f;
            const float ivb = (lb > 0.0f) ? 1.0f / lb : 0.0f;
            u16* ya = &QY[((size_t)((b_ * 4096 + base_r + l15) * 8 + h)) * 64];
            u16* yb = ya + 16 * 8 * 64;
#pragma unroll
            for (int n = 0; n < 4; n++) {
                f32x4 sa4 = *(const f32x4*)&OxA[n][lane][0];
                f32x4 sb4 = *(const f32x4*)&OxB[n][lane][0];
                ushort4 wa;
                wa.x = f2bf((oa[n][0] + sa4[0]) * iva);
                wa.y = f2bf((oa[n][1] + sa4[1]) * iva);
                wa.z = f2bf((oa[n][2] + sa4[2]) * iva);
                wa.w = f2bf((oa[n][3] + sa4[3]) * iva);
                *(ushort4*)&ya[n * 16 + quad * 4] = wa;
                ushort4 wb;
                wb.x = f2bf((ob[n][0] + sb4[0]) * ivb);
                wb.y = f2bf((ob[n][1] + sb4[1]) * ivb);
                wb.z = f2bf((ob[n][2] + sb4[2]) * ivb);
                wb.w = f2bf((ob[n][3] + sb4[3]) * ivb);
                *(ushort4*)&yb[n * 16 + quad * 4] = wb;
            }
        }
        __syncthreads();
    }
#undef LOADK
#undef LOADV
#undef TILE_A
#undef TILE_B
}

// ---------------------------------------------------------------------------
// GEMM3: out = y @ Wo^T + bo, operand-swapped -> float4 stores.
// Same dbuf + counted-vmcnt K-loop as GEMM1.
// ---------------------------------------------------------------------------
__global__ __launch_bounds__(256) void gemm_o_bf(
    const u16* __restrict__ X, const u16* __restrict__ W,
    const float* __restrict__ bias, float* __restrict__ Out)
{
    __shared__ u16 As[2 * 128 * 32];
    __shared__ u16 Bs[2 * 128 * 32];
    const int K = 512;
    const int tid = threadIdx.x, wave = tid >> 6, lane = tid & 63;
    const int l15 = lane & 15, quad = lane >> 4;
    const int bm = blockIdx.x * 128, bn = blockIdx.y * 128;
    const int wr = wave >> 1, wc = wave & 1;
    const int arow = lane >> 2;
    const int acol = (lane & 3) * 8;

    f32x4 acc[4][4] = {};
#pragma unroll
    for (int ii = 0; ii < 2; ii++) {
        const int inst = wave * 2 + ii;
        const int row = inst * 16 + arow;
        load_lds16(&X[(bm + row) * K + acol], &As[inst * 512]);
        load_lds16(&W[(bn + row) * K + acol], &Bs[inst * 512]);
    }
    int cur = 0;
    for (int k0 = 0; k0 < K; k0 += 32) {
        __builtin_amdgcn_s_barrier();
        if (k0 + 32 < K) {
            const int nb = (cur ^ 1) * 4096;
#pragma unroll
            for (int ii = 0; ii < 2; ii++) {
                const int inst = wave * 2 + ii;
                const int row = inst * 16 + arow;
                load_lds16(&X[(bm + row) * K + k0 + 32 + acol], &As[nb + inst * 512]);
                load_lds16(&W[(bn + row) * K + k0 + 32 + acol], &Bs[nb + inst * 512]);
            }
            asm volatile("s_waitcnt vmcnt(4)" ::: "memory");
        } else {
            asm volatile("s_waitcnt vmcnt(0)" ::: "memory");
        }
        __builtin_amdgcn_s_barrier();
        const int cb = cur * 4096;
        bf16x8 a[4], b[4];
#pragma unroll
        for (int i = 0; i < 4; i++)
            a[i] = *(const bf16x8*)&As[cb + (wr * 64 + i * 16 + l15) * 32 + quad * 8];
#pragma unroll
        for (int j = 0; j < 4; j++)
            b[j] = *(const bf16x8*)&Bs[cb + (wc * 64 + j * 16 + l15) * 32 + quad * 8];
#pragma unroll
        for (int i = 0; i < 4; i++)
#pragma unroll
            for (int j = 0; j < 4; j++)
                acc[i][j] = MFMA(b[i], a[j], acc[i][j]);
        cur ^= 1;
    }
#pragma unroll
    for (int i = 0; i < 4; i++) {
        const int n0 = bn + wc * 64 + i * 16 + quad * 4;
        const float4 bv = *(const float4*)&bias[n0];
#pragma unroll
        for (int j = 0; j < 4; j++) {
            const int m = bm + wr * 64 + j * 16 + l15;
            float4 ov;
            ov.x = acc[i][j][0] + bv.x;
            ov.y = acc[i][j][1] + bv.y;
            ov.z = acc[i][j][2] + bv.z;
            ov.w = acc[i][j][3] + bv.w;
            *(float4*)&Out[(size_t)m * 512 + n0] = ov;
        }
    }
}

extern "C" void kernel_launch(void* const* d_in, const int* in_sizes, int n_in,
                              void* d_out, int out_size, void* d_ws, size_t ws_size,
                              hipStream_t stream) {
    (void)in_sizes; (void)n_in; (void)out_size; (void)ws_size;
    const float* x    = (const float*)d_in[0];
    const float* Wqkv = (const float*)d_in[1];
    const float* bqkv = (const float*)d_in[2];
    const float* Wo   = (const float*)d_in[3];
    const float* bo   = (const float*)d_in[4];
    float* out = (float*)d_out;

    u16* qy_ws = (u16*)d_ws;                 // 8 MiB  [b][s][h][hd] (Q -> Y in place)
    u16* kf_ws = qy_ws + 4194304;            // 8 MiB  Kf frag-major
    u16* vf_ws = kf_ws + 4194304;            // 8 MiB  Vf frag-major
    float* ml  = (float*)(vf_ws + 4194304);  // 1 MiB region (unused, kept for layout)
    u16* wqkvb = (u16*)(ml + 262144);        // 1.5 MiB bf16 Wqkv
    u16* wob   = wqkvb + 786432;             // 0.5 MiB bf16 Wo
    u16* xb    = (u16*)d_out;                // 8 MiB bf16 x (dead after gemm1)

    cvt_all<<<5120, 256, 0, stream>>>(x, Wqkv, Wo, xb, wqkvb, wob);
    gemm_qkv_bf<<<dim3(64, 12), 256, 0, stream>>>(xb, wqkvb, bqkv, qy_ws, kf_ws, vf_ws);
    attn_k<<<dim3(16, 64), 128, 0, stream>>>(qy_ws, kf_ws, vf_ws);
    gemm_o_bf<<<dim3(64, 4), 256, 0, stream>>>(qy_ws, wob, bo, out);
}